// Round 13
// baseline (707.228 us; speedup 1.0000x reference)
//
#include <hip/hip_runtime.h>
#include <hip/hip_bf16.h>
#include <math.h>

#define T_LEN 512
#define B_SZ  256
#define I_SZ  300
#define H_SZ  64
#define G3    192   // 3H
#define TPG   3072  // 192*16 h16 per t-slice of one group
#define HPAD  80    // h-table row stride (h16): 160 B, 16B-aligned

typedef float    f4v __attribute__((ext_vector_type(4)));
typedef _Float16 h4v __attribute__((ext_vector_type(4)));
typedef _Float16 h8v __attribute__((ext_vector_type(8)));

__device__ __forceinline__ float sigm_f(float x) {
    return __builtin_amdgcn_rcpf(1.f + __expf(-x));
}
__device__ __forceinline__ float tanh_f(float x) {
    float a = fabsf(x);
    float e = __expf(2.f * a);
    float t = 1.f - 2.f * __builtin_amdgcn_rcpf(1.f + e);
    return copysignf(t, x);
}

// LDS-only block barrier (verified R6/R8): wait + s_barrier fused in ONE asm
// with "memory" clobber — no IR hoisting across, no vmcnt drain.
__device__ __forceinline__ void lds_barrier() {
    __builtin_amdgcn_sched_barrier(0);
    asm volatile("s_waitcnt lgkmcnt(0)\n\ts_barrier" ::: "memory");
    __builtin_amdgcn_sched_barrier(0);
}

// ---------------------------------------------------------------------------
// Kernel 1 (R13 rewrite): 256 blocks x 512 threads — EXACTLY 1 block/CU, all
// co-resident by construction (R8-R12 counters showed the 2048-block version
// averaged ~0.3 blocks/CU: OccupancyPercent 3.4% vs 25% theoretical — the
// kernel ran ~latency-serialized, ~190-230 µs vs a ~45 µs roofline floor).
//   * W (f16, zero-padded past k=299) preloaded ONCE into 120 KB LDS with the
//     verified tile/swizzle layout; ONE __syncthreads; then the whole main
//     loop is BARRIER-FREE.
//   * x loads go global -> fragment directly: lane (kgrp,fr) needs
//     x[b=G*16+fr][t][k0..k0+7] = 2 float4 — no LDS staging, no cvt
//     round-trip. W's zero-pad makes unguarded x tail garbage harmless;
//     the two float4s that could run past the buffer are predicated.
//   * Block = (d, G, tcc): 4 t-chunks x 5 kc x 48 MFMA/wave; wave owns 2 t.
//   * Epilogue: verified operand-swapped C[m=g][n=b] -> [t][b][g] h4v stores.
// ---------------------------------------------------------------------------
#define KC  64
#define NKC 5     // ceil(300/64)

__device__ __forceinline__ int stage_off(int j, int srow, int skq) {
    int g2 = (skq >> 1) & 3;
    return j * 1024 + (skq >> 3) * 512 + g2 * 128 + ((srow ^ (g2 << 1)) << 3) + (skq & 1) * 4;
}
__device__ __forceinline__ int frag_off(int tile, int kh, int lane) {
    int kgrp = lane >> 4, fr = lane & 15;
    return tile * 1024 + kh * 512 + kgrp * 128 + (((fr ^ (kgrp << 1))) << 3);
}

__global__ __launch_bounds__(512, 2) void proj_gemm(
    const float* __restrict__ x,
    const float* __restrict__ Wf, const float* __restrict__ bf,
    const float* __restrict__ Wb, const float* __restrict__ bb,
    _Float16* __restrict__ xp)
{
    __shared__ _Float16 Bp[NKC * 12 * 1024];   // 120 KB: full W as f16 tiles

    const int tid = threadIdx.x;          // 0..511
    const int bid = blockIdx.x;           // 0..255
    const int d   = bid >> 7;
    const int G   = (bid >> 3) & 15;
    const int tcc = bid & 7;              // 64-t slab

    const float* W    = d ? Wb : Wf;
    const float* bias = d ? bb : bf;

    // ---- W preload: 60 tiles (5 kc x 12 gt), zero-padded past k=299 ----
    {
        const int srow5 = tid >> 4;       // 0..31
        const int skq   = tid & 15;
        const int row   = srow5 & 15;
        const int jW    = srow5 >> 4;     // 0..1 -> tiles jW*6 .. +5
        #pragma unroll
        for (int kc = 0; kc < NKC; ++kc) {
            const bool valid = (kc * KC + skq * 4) <= 296;
            #pragma unroll
            for (int jj = 0; jj < 6; ++jj) {
                const int tile = jW * 6 + jj;
                float4 v = valid ? *(const float4*)(W + (size_t)(tile * 16 + row) * I_SZ + kc * KC + skq * 4)
                                 : float4{0.f, 0.f, 0.f, 0.f};
                h4v c = { (_Float16)v.x, (_Float16)v.y, (_Float16)v.z, (_Float16)v.w };
                *(h4v*)&Bp[kc * 12288 + stage_off(tile, row, skq)] = c;
            }
        }
    }
    __syncthreads();   // the ONLY barrier — main loop is barrier-free

    const int lane = tid & 63;
    const int w    = tid >> 6;            // 0..7: wave owns 2 t per t-chunk
    const int kgrp = lane >> 4;
    const int fr   = lane & 15;

    const float* xrow = x + (size_t)(G * 16 + fr) * T_LEN * I_SZ;

    const int col  = lane & 15;           // batch (epilogue)
    const int rowq = lane >> 4;           // g-quad (epilogue)
    _Float16* obase = xp + (size_t)(d * 16 + G) * T_LEN * TPG;

    for (int tch = 0; tch < 4; ++tch) {
        const int t0 = tcc * 64 + tch * 16 + w * 2;   // wave's first t

        f4v acc[2][12];
        #pragma unroll
        for (int t2 = 0; t2 < 2; ++t2)
            #pragma unroll
            for (int gt = 0; gt < 12; ++gt) acc[t2][gt] = (f4v)0.f;

        #pragma unroll
        for (int kc = 0; kc < NKC; ++kc) {
            // direct global->frag x loads (8 float4, guarded vs row end)
            h8v xb[2][2];   // [t2][kh] — all indices compile-time (rule #20)
            #pragma unroll
            for (int t2 = 0; t2 < 2; ++t2) {
                const float* xt = xrow + (size_t)(t0 + t2) * I_SZ;
                #pragma unroll
                for (int kh = 0; kh < 2; ++kh) {
                    const int k0 = kc * KC + kh * 32 + kgrp * 8;
                    float4 lo = (k0     <= 296) ? *(const float4*)(xt + k0)     : float4{0.f,0.f,0.f,0.f};
                    float4 hi = (k0 + 4 <= 296) ? *(const float4*)(xt + k0 + 4) : float4{0.f,0.f,0.f,0.f};
                    xb[t2][kh] = h8v{(_Float16)lo.x,(_Float16)lo.y,(_Float16)lo.z,(_Float16)lo.w,
                                     (_Float16)hi.x,(_Float16)hi.y,(_Float16)hi.z,(_Float16)hi.w};
                }
            }
            #pragma unroll
            for (int kh = 0; kh < 2; ++kh) {
                #pragma unroll
                for (int gt = 0; gt < 12; ++gt) {
                    h8v wf = *(const h8v*)&Bp[kc * 12288 + frag_off(gt, kh, lane)];
                    // operand swap: A = W (m=g), B = x (n=batch)
                    acc[0][gt] = __builtin_amdgcn_mfma_f32_16x16x32_f16(wf, xb[0][kh], acc[0][gt], 0, 0, 0);
                    acc[1][gt] = __builtin_amdgcn_mfma_f32_16x16x32_f16(wf, xb[1][kh], acc[1][gt], 0, 0, 0);
                }
            }
        }

        // epilogue: C[m=g][n=b] -> xp[t][b][g], one h4v per (t2, gt)
        #pragma unroll
        for (int t2 = 0; t2 < 2; ++t2) {
            _Float16* ot = obase + (size_t)(t0 + t2) * TPG;
            #pragma unroll
            for (int gt = 0; gt < 12; ++gt) {
                float4 bv4 = *(const float4*)(bias + gt * 16 + rowq * 4);
                h4v c = { (_Float16)(acc[t2][gt][0] + bv4.x),
                          (_Float16)(acc[t2][gt][1] + bv4.y),
                          (_Float16)(acc[t2][gt][2] + bv4.z),
                          (_Float16)(acc[t2][gt][3] + bv4.w) };
                *(h4v*)(ot + col * G3 + gt * 16 + rowq * 4) = c;
            }
        }
    }
}

// ---------------------------------------------------------------------------
// Kernel 2: GRU scan (R8/R12, verified — UNTOUCHED).
// 128 blocks x 4 waves, batch-split 4x, quad-replication A[m]=h[m>>2],
// 1 pointwise el/lane, [t][b][g] coalesced loads, fused lds_barrier.
// ---------------------------------------------------------------------------
__global__ __launch_bounds__(256) void gru_scan(
    const _Float16* __restrict__ xp2,   // [d][G][t][b16][g192]
    const float* __restrict__ Whf, const float* __restrict__ bhf,
    const float* __restrict__ Whb, const float* __restrict__ bhb,
    float* __restrict__ feat)
{
    const int tid  = threadIdx.x;
    const int lane = tid & 63;
    const int w    = tid >> 6;          // wave = u-slice
    const int blk  = blockIdx.x;        // 0..127
    const int d    = blk >> 6;
    const int G    = (blk >> 2) & 15;
    const int sub  = blk & 3;           // batch sub-group (4 batches)
    const int col  = lane & 15;
    const int quad = lane >> 4;
    const int u    = w * 16 + col;      // hidden unit owned by this lane
    const int bm   = sub * 4 + quad;    // batch-in-G owned by this lane

    const float* Whh = d ? Whb : Whf;
    const float* bhh = d ? bhb : bhf;

    h8v wb[3][2];
    f4v accb[3];
    int loff[3];
    #pragma unroll
    for (int g = 0; g < 3; ++g) {
        const int n = g * 64 + u;
        const float* wrow = Whh + (size_t)n * 64;
        #pragma unroll
        for (int c = 0; c < 2; ++c) {
            float4 w0 = *(const float4*)(wrow + c * 32 + quad * 8);
            float4 w1 = *(const float4*)(wrow + c * 32 + quad * 8 + 4);
            wb[g][c] = h8v{(_Float16)w0.x, (_Float16)w0.y, (_Float16)w0.z, (_Float16)w0.w,
                           (_Float16)w1.x, (_Float16)w1.y, (_Float16)w1.z, (_Float16)w1.w};
        }
        float bn = bhh[n];
        accb[g] = f4v{bn, bn, bn, bn};
        loff[g] = bm * G3 + n;          // [t][b][g]: contiguous 32B per quad
    }

    __shared__ _Float16 hs[2][4 * HPAD];
    for (int i = tid; i < 4 * HPAD; i += 256) hs[0][i] = (_Float16)0.f;
    float hold = 0.f;

    const long tstep = d ? -(long)TPG : (long)TPG;
    const _Float16* base = xp2 + (size_t)(d * 16 + G) * T_LEN * TPG
                               + (size_t)(d ? T_LEN - 1 : 0) * TPG;

    _Float16 px[2][3];
    #pragma unroll
    for (int g = 0; g < 3; ++g) {
        px[0][g] = base[loff[g]];
        px[1][g] = base[tstep + loff[g]];
    }
    const _Float16* pnext = base + 2 * tstep;

    const int off_first = d ? 192 : 0;
    const int off_last  = d ? 64 : 128;

    __syncthreads();   // once: hs init visible

    for (int s = 0; s < T_LEN; s += 2) {
        #pragma unroll
        for (int j = 0; j < 2; ++j) {
            const int sj = s + j;
            const _Float16* hrd = hs[j];
            _Float16*       hwr = hs[j ^ 1];

            h8v a0 = *(const h8v*)&hrd[(col >> 2) * HPAD + quad * 8];
            h8v a1 = *(const h8v*)&hrd[(col >> 2) * HPAD + 32 + quad * 8];

            f4v gh[3];
            #pragma unroll
            for (int g = 0; g < 3; ++g) {
                f4v t0 = __builtin_amdgcn_mfma_f32_16x16x32_f16(a0, wb[g][0], accb[g], 0, 0, 0);
                gh[g]  = __builtin_amdgcn_mfma_f32_16x16x32_f16(a1, wb[g][1], t0, 0, 0, 0);
            }

            _Float16 xc0 = px[j][0], xc1 = px[j][1], xc2 = px[j][2];
            if (sj + 2 < T_LEN) {
                #pragma unroll
                for (int g = 0; g < 3; ++g)
                    px[j][g] = pnext[loff[g]];
                pnext += tstep;
            }

            {
                float r = sigm_f((float)xc0 + gh[0][0]);
                float z = sigm_f((float)xc1 + gh[1][0]);
                float n = tanh_f((float)xc2 + r * gh[2][0]);
                float h = fmaf(z, hold - n, n);
                hold = h;
                hwr[quad * HPAD + u] = (_Float16)h;
            }

            if (sj == 0)
                feat[(G * 16 + bm) * 256 + off_first + u] = hold;
            if (sj == T_LEN - 1)
                feat[(G * 16 + bm) * 256 + off_last + u] = hold;

            lds_barrier();
        }
    }
}

// ---------------------------------------------------------------------------
// Kernel 3: MLP head. feat[b][256] -> 32 (LeakyReLU) -> 1
// ---------------------------------------------------------------------------
__global__ __launch_bounds__(64) void head_k(
    const float* __restrict__ feat,
    const float* __restrict__ W1, const float* __restrict__ b1,
    const float* __restrict__ W2, const float* __restrict__ b2,
    float* __restrict__ out)
{
    __shared__ float fs[256];
    const int b = blockIdx.x;
    const int tid = threadIdx.x;
    *(float4*)&fs[tid * 4] = *(const float4*)&feat[b * 256 + tid * 4];
    __syncthreads();
    float v = 0.f;
    if (tid < 32) {
        float a = b1[tid];
        const float4* Wv = (const float4*)(W1 + tid * 256);
        const float4* fv = (const float4*)fs;
        #pragma unroll 8
        for (int k = 0; k < 64; ++k) {
            float4 wv = Wv[k], f = fv[k];
            a += wv.x * f.x + wv.y * f.y + wv.z * f.z + wv.w * f.w;
        }
        a = a >= 0.f ? a : 0.01f * a;
        v = a * W2[tid];
    }
    #pragma unroll
    for (int off = 16; off > 0; off >>= 1) v += __shfl_down(v, off);
    if (tid == 0) out[b] = v + b2[0];
}

// ---------------------------------------------------------------------------
extern "C" void kernel_launch(void* const* d_in, const int* in_sizes, int n_in,
                              void* d_out, int out_size, void* d_ws, size_t ws_size,
                              hipStream_t stream)
{
    const float* x    = (const float*)d_in[0];
    const float* Wihf = (const float*)d_in[1];
    const float* Whhf = (const float*)d_in[2];
    const float* bihf = (const float*)d_in[3];
    const float* bhhf = (const float*)d_in[4];
    const float* Wihb = (const float*)d_in[5];
    const float* Whhb = (const float*)d_in[6];
    const float* bihb = (const float*)d_in[7];
    const float* bhhb = (const float*)d_in[8];
    const float* W1   = (const float*)d_in[9];
    const float* b1   = (const float*)d_in[10];
    const float* W2   = (const float*)d_in[11];
    const float* b2   = (const float*)d_in[12];
    float* out = (float*)d_out;

    _Float16* xp2  = (_Float16*)d_ws;                        // [d][G][t][b][g], 100.7 MB
    float*    feat = (float*)((char*)d_ws + (size_t)2 * B_SZ * T_LEN * G3 * 2);

    proj_gemm<<<256, 512, 0, stream>>>(x, Wihf, bihf, Wihb, bihb, xp2);
    gru_scan<<<128, 256, 0, stream>>>(xp2, Whhf, bhhf, Whhb, bhhb, feat);
    head_k<<<256, 64, 0, stream>>>(feat, W1, b1, W2, b2, out);
}